// Round 1
// baseline (1076.186 us; speedup 1.0000x reference)
//
#include <hip/hip_runtime.h>

typedef __bf16 bf16x8 __attribute__((ext_vector_type(8)));
typedef float f32x4 __attribute__((ext_vector_type(4)));
typedef short short8 __attribute__((ext_vector_type(8)));

union S8 { short8 v; unsigned short u[8]; };

__device__ __forceinline__ float b2f(unsigned short u) {
    unsigned int x = ((unsigned int)u) << 16;
    float f; __builtin_memcpy(&f, &x, 4); return f;
}
__device__ __forceinline__ unsigned short f2b(float f) {
    unsigned int x; __builtin_memcpy(&x, &f, 4);
    unsigned int r = x + 0x7fffu + ((x >> 16) & 1u);   // RNE
    return (unsigned short)(r >> 16);
}

__device__ __forceinline__ void gload_lds16(const unsigned short* g, unsigned short* l) {
    __builtin_amdgcn_global_load_lds(
        (const __attribute__((address_space(1))) void*)g,
        (__attribute__((address_space(3))) void*)l, 16, 0, 0);
}

// ---------------- prep: vis mask + cos/sin tables ----------------
__global__ void prep_kernel(const int* __restrict__ tt, const int* __restrict__ pos,
                            const float* __restrict__ invf,
                            unsigned char* __restrict__ mask,
                            float* __restrict__ ct, float* __restrict__ st, int S) {
    int i = blockIdx.x * 256 + threadIdx.x;
    if (i >= S * 64) return;
    int s = i >> 6, d = i & 63;
    float f = (float)pos[s] * invf[d];
    ct[i] = cosf(f);
    st[i] = sinf(f);
    if (d == 0) mask[s] = (s < S - 1 && tt[s] == 1 && tt[s + 1] == 1) ? 1 : 0;
}

// ---------------- f32 -> bf16 convert (vectorized, grid-stride) ----------------
__global__ void cvt_f32_bf16(const float* __restrict__ in, unsigned short* __restrict__ out, long n) {
    long i = ((long)blockIdx.x * blockDim.x + threadIdx.x) * 4;
    long stride = (long)gridDim.x * blockDim.x * 4;
    for (; i < n; i += stride) {
        float4 v = *(const float4*)(in + i);
        ushort4 u;
        u.x = f2b(v.x); u.y = f2b(v.y); u.z = f2b(v.z); u.w = f2b(v.w);
        *(ushort4*)(out + i) = u;
    }
}

// ---------------- RoPE in-place on bf16 qkv ----------------
__global__ void rope_kernel(unsigned short* __restrict__ qkv,
                            const float* __restrict__ ct, const float* __restrict__ st, int S) {
    int i = blockIdx.x * 256 + threadIdx.x;
    if (i >= S * 32 * 2 * 8) return;
    int c  = i & 7;
    int qk = (i >> 3) & 1;
    int h  = (i >> 4) & 31;
    int s  = i >> 9;
    size_t base = (size_t)s * 12288 + (size_t)qk * 4096 + h * 128 + c * 8;
    S8 x1, x2, y1, y2;
    x1.v = *(const short8*)(qkv + base);
    x2.v = *(const short8*)(qkv + base + 64);
    #pragma unroll
    for (int j = 0; j < 8; ++j) {
        float cc = ct[s * 64 + c * 8 + j];
        float ss = st[s * 64 + c * 8 + j];
        float a = b2f(x1.u[j]), b = b2f(x2.u[j]);
        y1.u[j] = f2b(a * cc - b * ss);
        y2.u[j] = f2b(b * cc + a * ss);
    }
    *(short8*)(qkv + base)      = y1.v;
    *(short8*)(qkv + base + 64) = y2.v;
}

// ---------------- V transpose: qkv v-part [S][4096] -> vt [4096][S] ----------------
__global__ void transpose_v(const unsigned short* __restrict__ qkv,
                            unsigned short* __restrict__ vt, int S) {
    __shared__ unsigned short tile[64][72];
    int s0 = blockIdx.x * 64;
    int hd0 = blockIdx.y * 64;
    int t = threadIdx.x;
    #pragma unroll
    for (int it = 0; it < 2; ++it) {
        int c = it * 256 + t;
        int sl = c >> 3, k8 = (c & 7) << 3;
        S8 v; v.v = *(const short8*)(qkv + (size_t)(s0 + sl) * 12288 + 8192 + hd0 + k8);
        #pragma unroll
        for (int j = 0; j < 8; ++j) tile[sl][k8 + j] = v.u[j];
    }
    __syncthreads();
    #pragma unroll
    for (int it = 0; it < 2; ++it) {
        int c = it * 256 + t;
        int hdl = c >> 3, sk = (c & 7) << 3;
        S8 o;
        #pragma unroll
        for (int j = 0; j < 8; ++j) o.u[j] = tile[sk + j][hdl];
        *(short8*)(vt + (size_t)(hd0 + hdl) * S + s0 + sk) = o.v;
    }
}

// ---------------- masked GEMM: C[m][n] = sum_k A[m][k]*B[n][k], rows where mask==want ----------------
// 128x128 tile, BK=32, 4 waves, global_load_lds w16, XOR chunk swizzle (2-way conflicts)
template <int OUT_BF16>
__global__ void __launch_bounds__(256, 2)
gemm_bt_masked(const unsigned short* __restrict__ A,
               const unsigned short* __restrict__ B,
               void* __restrict__ Cv,
               int M, int N, int K,
               const unsigned char* __restrict__ mask, int want) {
    __shared__ unsigned short sA[128 * 32];
    __shared__ unsigned short sB[128 * 32];
    __shared__ int s_any;
    int t = threadIdx.x;
    int m0 = blockIdx.y * 128;
    int n0 = blockIdx.x * 128;
    if (t == 0) s_any = 0;
    __syncthreads();
    if (t < 128 && mask[m0 + t] == (unsigned char)want) s_any = 1;
    __syncthreads();
    if (!s_any) return;

    int lane = t & 63;
    int w = t >> 6;
    int wm = w >> 1, wn = w & 1;
    int l15 = lane & 15, g = lane >> 4;

    // staging: chunk c covers rows c*16..c*16+15, lane's 16B goes at LDS c*1024 + lane*16
    int c0 = w * 2, c1 = c0 + 1;
    int r0 = c0 * 16 + (lane >> 2);
    int r1 = c1 * 16 + (lane >> 2);
    int pc = lane & 3;
    const unsigned short* gA0 = A + (size_t)(m0 + r0) * K + ((pc ^ ((r0 >> 1) & 3)) << 3);
    const unsigned short* gA1 = A + (size_t)(m0 + r1) * K + ((pc ^ ((r1 >> 1) & 3)) << 3);
    const unsigned short* gB0 = B + (size_t)(n0 + r0) * K + ((pc ^ ((r0 >> 1) & 3)) << 3);
    const unsigned short* gB1 = B + (size_t)(n0 + r1) * K + ((pc ^ ((r1 >> 1) & 3)) << 3);
    unsigned short* lA0 = sA + c0 * 512;
    unsigned short* lA1 = sA + c1 * 512;
    unsigned short* lB0 = sB + c0 * 512;
    unsigned short* lB1 = sB + c1 * 512;

    f32x4 acc[4][4];
    #pragma unroll
    for (int i = 0; i < 4; ++i)
        #pragma unroll
        for (int j = 0; j < 4; ++j) acc[i][j] = (f32x4){0.f, 0.f, 0.f, 0.f};

    for (int k0 = 0; k0 < K; k0 += 32) {
        __syncthreads();
        gload_lds16(gA0 + k0, lA0);
        gload_lds16(gA1 + k0, lA1);
        gload_lds16(gB0 + k0, lB0);
        gload_lds16(gB1 + k0, lB1);
        __syncthreads();
        bf16x8 af[4], bfr[4];
        #pragma unroll
        for (int i = 0; i < 4; ++i) {
            int ar = wm * 64 + i * 16 + l15;
            int ca = g ^ ((ar >> 1) & 3);
            af[i] = *(const bf16x8*)(sA + ar * 32 + ca * 8);
            int br = wn * 64 + i * 16 + l15;
            int cb = g ^ ((br >> 1) & 3);
            bfr[i] = *(const bf16x8*)(sB + br * 32 + cb * 8);
        }
        #pragma unroll
        for (int i = 0; i < 4; ++i)
            #pragma unroll
            for (int j = 0; j < 4; ++j)
                acc[i][j] = __builtin_amdgcn_mfma_f32_16x16x32_bf16(af[i], bfr[j], acc[i][j], 0, 0, 0);
    }

    #pragma unroll
    for (int i = 0; i < 4; ++i) {
        int rbase = m0 + wm * 64 + i * 16 + g * 4;
        #pragma unroll
        for (int r = 0; r < 4; ++r) {
            int row = rbase + r;
            if (mask[row] != (unsigned char)want) continue;
            #pragma unroll
            for (int j = 0; j < 4; ++j) {
                int col = n0 + wn * 64 + j * 16 + l15;
                float vv = acc[i][j][r];
                if (OUT_BF16) ((unsigned short*)Cv)[(size_t)row * N + col] = f2b(vv);
                else          ((float*)Cv)[(size_t)row * N + col] = vv;
            }
        }
    }
}

// ---------------- flash attention: block=(qtile 64, head), 4 waves x 16 q-rows ----------------
__global__ void __launch_bounds__(256, 2)
attn_kernel(const unsigned short* __restrict__ qkv,
            const unsigned short* __restrict__ vt,
            unsigned short* __restrict__ ctx, int S) {
    __shared__ unsigned short pls[4][16 * 32];
    const float scale = 0.08838834764831845f;  // 1/sqrt(128)
    int h = blockIdx.y;
    int qt = blockIdx.x;
    int t = threadIdx.x, lane = t & 63, w = t >> 6;
    int q0 = qt * 64 + w * 16;
    int l15 = lane & 15, g = lane >> 4;

    bf16x8 qf[4];
    {
        const unsigned short* qb = qkv + (size_t)(q0 + l15) * 12288 + h * 128 + g * 8;
        #pragma unroll
        for (int kk = 0; kk < 4; ++kk) qf[kk] = *(const bf16x8*)(qb + kk * 32);
    }
    f32x4 oacc[8];
    #pragma unroll
    for (int dc = 0; dc < 8; ++dc) oacc[dc] = (f32x4){0.f, 0.f, 0.f, 0.f};
    float mrun[4], lrun[4];
    #pragma unroll
    for (int r = 0; r < 4; ++r) { mrun[r] = -__builtin_inff(); lrun[r] = 0.f; }

    int ntiles = (q0 + 16 + 31) >> 5;
    for (int kt = 0; kt < ntiles; ++kt) {
        int kb = kt << 5;
        float sv[2][4];
        #pragma unroll
        for (int jh = 0; jh < 2; ++jh) {
            f32x4 sacc = (f32x4){0.f, 0.f, 0.f, 0.f};
            int key = kb + jh * 16 + l15;
            const unsigned short* kbp = qkv + (size_t)key * 12288 + 4096 + h * 128 + g * 8;
            #pragma unroll
            for (int kk = 0; kk < 4; ++kk) {
                bf16x8 kf = *(const bf16x8*)(kbp + kk * 32);
                sacc = __builtin_amdgcn_mfma_f32_16x16x32_bf16(qf[kk], kf, sacc, 0, 0, 0);
            }
            #pragma unroll
            for (int r = 0; r < 4; ++r) {
                int qrow = q0 + g * 4 + r;
                sv[jh][r] = (key <= qrow) ? sacc[r] * scale : -__builtin_inff();
            }
        }
        #pragma unroll
        for (int r = 0; r < 4; ++r) {
            float tm = fmaxf(sv[0][r], sv[1][r]);
            tm = fmaxf(tm, __shfl_xor(tm, 1));
            tm = fmaxf(tm, __shfl_xor(tm, 2));
            tm = fmaxf(tm, __shfl_xor(tm, 4));
            tm = fmaxf(tm, __shfl_xor(tm, 8));
            float mnew = fmaxf(mrun[r], tm);
            float corr = __expf(mrun[r] - mnew);
            float p0 = __expf(sv[0][r] - mnew);
            float p1 = __expf(sv[1][r] - mnew);
            float ps = p0 + p1;
            ps += __shfl_xor(ps, 1);
            ps += __shfl_xor(ps, 2);
            ps += __shfl_xor(ps, 4);
            ps += __shfl_xor(ps, 8);
            lrun[r] = lrun[r] * corr + ps;
            mrun[r] = mnew;
            #pragma unroll
            for (int dc = 0; dc < 8; ++dc) oacc[dc][r] *= corr;
            pls[w][(g * 4 + r) * 32 + l15]      = f2b(p0);
            pls[w][(g * 4 + r) * 32 + 16 + l15] = f2b(p1);
        }
        bf16x8 pa = *(const bf16x8*)(&pls[w][l15 * 32 + g * 8]);
        #pragma unroll
        for (int dc = 0; dc < 8; ++dc) {
            const unsigned short* vb = vt + (size_t)(h * 128 + dc * 16 + l15) * S + kb + g * 8;
            bf16x8 vf = *(const bf16x8*)vb;
            oacc[dc] = __builtin_amdgcn_mfma_f32_16x16x32_bf16(pa, vf, oacc[dc], 0, 0, 0);
        }
    }
    #pragma unroll
    for (int dc = 0; dc < 8; ++dc)
        #pragma unroll
        for (int r = 0; r < 4; ++r) {
            int qrow = q0 + g * 4 + r;
            float o = oacc[dc][r] / lrun[r];
            ctx[(size_t)qrow * 4096 + h * 128 + dc * 16 + l15] = f2b(o);
        }
}

extern "C" void kernel_launch(void* const* d_in, const int* in_sizes, int n_in,
                              void* d_out, int out_size, void* d_ws, size_t ws_size,
                              hipStream_t stream) {
    const float* hs  = (const float*)d_in[0];
    const int* tt    = (const int*)d_in[1];
    const int* pos   = (const int*)d_in[2];
    const float* wqv = (const float*)d_in[3];
    const float* wql = (const float*)d_in[4];
    const float* wov = (const float*)d_in[5];
    const float* wol = (const float*)d_in[6];
    const float* invf= (const float*)d_in[7];
    float* out = (float*)d_out;

    const int S = 2048, D = 4096, K = 4096, N3 = 12288;

    char* ws = (char*)d_ws;
    size_t off = 0;
    auto alloc = [&](size_t bytes) {
        void* p = ws + off;
        off += (bytes + 255) & ~(size_t)255;
        return p;
    };
    unsigned char* mask = (unsigned char*)alloc(S);
    float* ct = (float*)alloc((size_t)S * 64 * 4);
    float* st = (float*)alloc((size_t)S * 64 * 4);
    unsigned short* hbf  = (unsigned short*)alloc((size_t)S * D * 2);
    unsigned short* qkv  = (unsigned short*)alloc((size_t)S * N3 * 2);
    unsigned short* vt   = (unsigned short*)alloc((size_t)S * D * 2);
    unsigned short* ctx  = (unsigned short*)alloc((size_t)S * D * 2);
    unsigned short* wbuf = (unsigned short*)alloc((size_t)N3 * K * 2);
    (void)ws_size; (void)n_in; (void)in_sizes; (void)out_size;

    prep_kernel<<<(S * 64 + 255) / 256, 256, 0, stream>>>(tt, pos, invf, mask, ct, st, S);
    cvt_f32_bf16<<<8192, 256, 0, stream>>>(hs, hbf, (long)S * D);

    cvt_f32_bf16<<<16384, 256, 0, stream>>>(wqv, wbuf, (long)N3 * K);
    gemm_bt_masked<1><<<dim3(96, 16), 256, 0, stream>>>(hbf, wbuf, qkv, S, N3, K, mask, 1);
    cvt_f32_bf16<<<16384, 256, 0, stream>>>(wql, wbuf, (long)N3 * K);
    gemm_bt_masked<1><<<dim3(96, 16), 256, 0, stream>>>(hbf, wbuf, qkv, S, N3, K, mask, 0);

    rope_kernel<<<(S * 32 * 16 + 255) / 256, 256, 0, stream>>>(qkv, ct, st, S);
    transpose_v<<<dim3(S / 64, D / 64), 256, 0, stream>>>(qkv, vt, S);
    attn_kernel<<<dim3(S / 64, 32), 256, 0, stream>>>(qkv, vt, ctx, S);

    cvt_f32_bf16<<<16384, 256, 0, stream>>>(wov, wbuf, (long)D * K);
    gemm_bt_masked<0><<<dim3(32, 16), 256, 0, stream>>>(ctx, wbuf, out, S, D, K, mask, 1);
    cvt_f32_bf16<<<16384, 256, 0, stream>>>(wol, wbuf, (long)D * K);
    gemm_bt_masked<0><<<dim3(32, 16), 256, 0, stream>>>(ctx, wbuf, out, S, D, K, mask, 0);
}

// Round 2
// 898.025 us; speedup vs baseline: 1.1984x; 1.1984x over previous
//
#include <hip/hip_runtime.h>

typedef __bf16 bf16x8 __attribute__((ext_vector_type(8)));
typedef float f32x4 __attribute__((ext_vector_type(4)));
typedef short short8 __attribute__((ext_vector_type(8)));

union S8 { short8 v; unsigned short u[8]; };

__device__ __forceinline__ float b2f(unsigned short u) {
    unsigned int x = ((unsigned int)u) << 16;
    float f; __builtin_memcpy(&f, &x, 4); return f;
}
__device__ __forceinline__ unsigned short f2b(float f) {
    unsigned int x; __builtin_memcpy(&x, &f, 4);
    unsigned int r = x + 0x7fffu + ((x >> 16) & 1u);   // RNE
    return (unsigned short)(r >> 16);
}

__device__ __forceinline__ void gload_lds16(const unsigned short* g, unsigned short* l) {
    __builtin_amdgcn_global_load_lds(
        (const __attribute__((address_space(1))) void*)g,
        (__attribute__((address_space(3))) void*)l, 16, 0, 0);
}

// ---------------- prep: vis mask + cos/sin tables ----------------
__global__ void prep_kernel(const int* __restrict__ tt, const int* __restrict__ pos,
                            const float* __restrict__ invf,
                            unsigned char* __restrict__ mask,
                            float* __restrict__ ct, float* __restrict__ st, int S) {
    int i = blockIdx.x * 256 + threadIdx.x;
    if (i >= S * 64) return;
    int s = i >> 6, d = i & 63;
    float f = (float)pos[s] * invf[d];
    ct[i] = cosf(f);
    st[i] = sinf(f);
    if (d == 0) mask[s] = (s < S - 1 && tt[s] == 1 && tt[s + 1] == 1) ? 1 : 0;
}

// ---------------- f32 -> bf16 convert (vectorized, grid-stride) ----------------
__global__ void cvt_f32_bf16(const float* __restrict__ in, unsigned short* __restrict__ out, long n) {
    long i = ((long)blockIdx.x * blockDim.x + threadIdx.x) * 4;
    long stride = (long)gridDim.x * blockDim.x * 4;
    for (; i < n; i += stride) {
        float4 v = *(const float4*)(in + i);
        ushort4 u;
        u.x = f2b(v.x); u.y = f2b(v.y); u.z = f2b(v.z); u.w = f2b(v.w);
        *(ushort4*)(out + i) = u;
    }
}

// ---------------- RoPE in-place on bf16 qkv ----------------
__global__ void rope_kernel(unsigned short* __restrict__ qkv,
                            const float* __restrict__ ct, const float* __restrict__ st, int S) {
    int i = blockIdx.x * 256 + threadIdx.x;
    if (i >= S * 32 * 2 * 8) return;
    int c  = i & 7;
    int qk = (i >> 3) & 1;
    int h  = (i >> 4) & 31;
    int s  = i >> 9;
    size_t base = (size_t)s * 12288 + (size_t)qk * 4096 + h * 128 + c * 8;
    S8 x1, x2, y1, y2;
    x1.v = *(const short8*)(qkv + base);
    x2.v = *(const short8*)(qkv + base + 64);
    #pragma unroll
    for (int j = 0; j < 8; ++j) {
        float cc = ct[s * 64 + c * 8 + j];
        float ss = st[s * 64 + c * 8 + j];
        float a = b2f(x1.u[j]), b = b2f(x2.u[j]);
        y1.u[j] = f2b(a * cc - b * ss);
        y2.u[j] = f2b(b * cc + a * ss);
    }
    *(short8*)(qkv + base)      = y1.v;
    *(short8*)(qkv + base + 64) = y2.v;
}

// ---------------- V transpose: qkv v-part [S][4096] -> vt [4096][S] ----------------
__global__ void transpose_v(const unsigned short* __restrict__ qkv,
                            unsigned short* __restrict__ vt, int S) {
    __shared__ unsigned short tile[64][72];
    int s0 = blockIdx.x * 64;
    int hd0 = blockIdx.y * 64;
    int t = threadIdx.x;
    #pragma unroll
    for (int it = 0; it < 2; ++it) {
        int c = it * 256 + t;
        int sl = c >> 3, k8 = (c & 7) << 3;
        S8 v; v.v = *(const short8*)(qkv + (size_t)(s0 + sl) * 12288 + 8192 + hd0 + k8);
        #pragma unroll
        for (int j = 0; j < 8; ++j) tile[sl][k8 + j] = v.u[j];
    }
    __syncthreads();
    #pragma unroll
    for (int it = 0; it < 2; ++it) {
        int c = it * 256 + t;
        int hdl = c >> 3, sk = (c & 7) << 3;
        S8 o;
        #pragma unroll
        for (int j = 0; j < 8; ++j) o.u[j] = tile[sk + j][hdl];
        *(short8*)(vt + (size_t)(hd0 + hdl) * S + s0 + sk) = o.v;
    }
}

// ---------------- masked GEMM: C[m][n] = sum_k A[m][k]*B[n][k], rows where mask==want ----------------
// 128x128 tile, BK=32, 4 waves, global_load_lds w16, XOR chunk swizzle (2-way conflicts)
template <int OUT_BF16>
__global__ void __launch_bounds__(256, 2)
gemm_bt_masked(const unsigned short* __restrict__ A,
               const unsigned short* __restrict__ B,
               void* __restrict__ Cv,
               int M, int N, int K,
               const unsigned char* __restrict__ mask, int want) {
    __shared__ unsigned short sA[128 * 32];
    __shared__ unsigned short sB[128 * 32];
    __shared__ int s_any;
    int t = threadIdx.x;
    int m0 = blockIdx.y * 128;
    int n0 = blockIdx.x * 128;
    if (t == 0) s_any = 0;
    __syncthreads();
    if (t < 128 && mask[m0 + t] == (unsigned char)want) s_any = 1;
    __syncthreads();
    if (!s_any) return;

    int lane = t & 63;
    int w = t >> 6;
    int wm = w >> 1, wn = w & 1;
    int l15 = lane & 15, g = lane >> 4;

    int c0 = w * 2, c1 = c0 + 1;
    int r0 = c0 * 16 + (lane >> 2);
    int r1 = c1 * 16 + (lane >> 2);
    int pc = lane & 3;
    const unsigned short* gA0 = A + (size_t)(m0 + r0) * K + ((pc ^ ((r0 >> 1) & 3)) << 3);
    const unsigned short* gA1 = A + (size_t)(m0 + r1) * K + ((pc ^ ((r1 >> 1) & 3)) << 3);
    const unsigned short* gB0 = B + (size_t)(n0 + r0) * K + ((pc ^ ((r0 >> 1) & 3)) << 3);
    const unsigned short* gB1 = B + (size_t)(n0 + r1) * K + ((pc ^ ((r1 >> 1) & 3)) << 3);
    unsigned short* lA0 = sA + c0 * 512;
    unsigned short* lA1 = sA + c1 * 512;
    unsigned short* lB0 = sB + c0 * 512;
    unsigned short* lB1 = sB + c1 * 512;

    f32x4 acc[4][4];
    #pragma unroll
    for (int i = 0; i < 4; ++i)
        #pragma unroll
        for (int j = 0; j < 4; ++j) acc[i][j] = (f32x4){0.f, 0.f, 0.f, 0.f};

    for (int k0 = 0; k0 < K; k0 += 32) {
        __syncthreads();
        gload_lds16(gA0 + k0, lA0);
        gload_lds16(gA1 + k0, lA1);
        gload_lds16(gB0 + k0, lB0);
        gload_lds16(gB1 + k0, lB1);
        __syncthreads();
        bf16x8 af[4], bfr[4];
        #pragma unroll
        for (int i = 0; i < 4; ++i) {
            int ar = wm * 64 + i * 16 + l15;
            int ca = g ^ ((ar >> 1) & 3);
            af[i] = *(const bf16x8*)(sA + ar * 32 + ca * 8);
            int br = wn * 64 + i * 16 + l15;
            int cb = g ^ ((br >> 1) & 3);
            bfr[i] = *(const bf16x8*)(sB + br * 32 + cb * 8);
        }
        #pragma unroll
        for (int i = 0; i < 4; ++i)
            #pragma unroll
            for (int j = 0; j < 4; ++j)
                acc[i][j] = __builtin_amdgcn_mfma_f32_16x16x32_bf16(af[i], bfr[j], acc[i][j], 0, 0, 0);
    }

    #pragma unroll
    for (int i = 0; i < 4; ++i) {
        int rbase = m0 + wm * 64 + i * 16 + g * 4;
        #pragma unroll
        for (int r = 0; r < 4; ++r) {
            int row = rbase + r;
            if (mask[row] != (unsigned char)want) continue;
            #pragma unroll
            for (int j = 0; j < 4; ++j) {
                int col = n0 + wn * 64 + j * 16 + l15;
                float vv = acc[i][j][r];
                if (OUT_BF16) ((unsigned short*)Cv)[(size_t)row * N + col] = f2b(vv);
                else          ((float*)Cv)[(size_t)row * N + col] = vv;
            }
        }
    }
}

// ---------------- flash attention v2: 64-key iterations, LPT order, swizzled P ----------------
// grid = (32 heads, 32 qtiles); qtl reversed so longest blocks dispatch first.
// block = 4 waves; wave w owns q-rows [qtl*64 + w*16, +16).
__global__ void __launch_bounds__(256, 2)
attn_kernel(const unsigned short* __restrict__ qkv,
            const unsigned short* __restrict__ vt,
            unsigned short* __restrict__ ctx, int S) {
    __shared__ unsigned short pls[4][16 * 64];
    const float scale = 0.08838834764831845f;  // 1/sqrt(128)
    int h = blockIdx.x;
    int qtl = (gridDim.y - 1) - blockIdx.y;     // LPT: big blocks first
    int t = threadIdx.x, lane = t & 63, w = t >> 6;
    int q0 = qtl * 64 + w * 16;
    int l15 = lane & 15, g = lane >> 4;

    bf16x8 qf[4];
    {
        const unsigned short* qb = qkv + (size_t)(q0 + l15) * 12288 + h * 128 + g * 8;
        #pragma unroll
        for (int kk = 0; kk < 4; ++kk) qf[kk] = *(const bf16x8*)(qb + kk * 32);
    }
    f32x4 oacc[8];
    #pragma unroll
    for (int dc = 0; dc < 8; ++dc) oacc[dc] = (f32x4){0.f, 0.f, 0.f, 0.f};
    float mrun[4], lrun[4];
    #pragma unroll
    for (int r = 0; r < 4; ++r) { mrun[r] = -__builtin_inff(); lrun[r] = 0.f; }

    int ntiles = qtl + 1;                        // 64-key tiles
    for (int kt = 0; kt < ntiles; ++kt) {
        int kb = kt << 6;
        // ---- QK^T: 4 independent 16-key sub-tiles (16 MFMAs, 4 chains) ----
        f32x4 sacc[4];
        #pragma unroll
        for (int jh = 0; jh < 4; ++jh) {
            sacc[jh] = (f32x4){0.f, 0.f, 0.f, 0.f};
            int key = kb + jh * 16 + l15;
            const unsigned short* kbp = qkv + (size_t)key * 12288 + 4096 + h * 128 + g * 8;
            #pragma unroll
            for (int kk = 0; kk < 4; ++kk) {
                bf16x8 kf = *(const bf16x8*)(kbp + kk * 32);
                sacc[jh] = __builtin_amdgcn_mfma_f32_16x16x32_bf16(qf[kk], kf, sacc[jh], 0, 0, 0);
            }
        }
        // ---- mask + scale ----
        float sv[4][4];
        #pragma unroll
        for (int jh = 0; jh < 4; ++jh) {
            int key = kb + jh * 16 + l15;
            #pragma unroll
            for (int r = 0; r < 4; ++r) {
                int qrow = q0 + g * 4 + r;
                sv[jh][r] = (key <= qrow) ? sacc[jh][r] * scale : -__builtin_inff();
            }
        }
        // ---- online softmax (per q-row), amortized over 64 keys ----
        #pragma unroll
        for (int r = 0; r < 4; ++r) {
            float tm = fmaxf(fmaxf(sv[0][r], sv[1][r]), fmaxf(sv[2][r], sv[3][r]));
            tm = fmaxf(tm, __shfl_xor(tm, 1));
            tm = fmaxf(tm, __shfl_xor(tm, 2));
            tm = fmaxf(tm, __shfl_xor(tm, 4));
            tm = fmaxf(tm, __shfl_xor(tm, 8));
            float mnew = fmaxf(mrun[r], tm);
            float corr = __expf(mrun[r] - mnew);
            float p[4], ps = 0.f;
            #pragma unroll
            for (int jh = 0; jh < 4; ++jh) { p[jh] = __expf(sv[jh][r] - mnew); ps += p[jh]; }
            ps += __shfl_xor(ps, 1);
            ps += __shfl_xor(ps, 2);
            ps += __shfl_xor(ps, 4);
            ps += __shfl_xor(ps, 8);
            lrun[r] = lrun[r] * corr + ps;
            mrun[r] = mnew;
            #pragma unroll
            for (int dc = 0; dc < 8; ++dc) oacc[dc][r] *= corr;
            int row = g * 4 + r;
            #pragma unroll
            for (int jh = 0; jh < 4; ++jh) {
                int key = jh * 16 + l15;
                pls[w][row * 64 + (key ^ ((row & 7) << 3))] = f2b(p[jh]);
            }
        }
        // ---- PV: P[16q x 64k] * V[64k x 128d] (16 MFMAs) ----
        bf16x8 pa0 = *(const bf16x8*)&pls[w][l15 * 64 + ((g ^ (l15 & 7)) << 3)];
        bf16x8 pa1 = *(const bf16x8*)&pls[w][l15 * 64 + (((4 + g) ^ (l15 & 7)) << 3)];
        #pragma unroll
        for (int dc = 0; dc < 8; ++dc) {
            const unsigned short* vb = vt + (size_t)(h * 128 + dc * 16 + l15) * S + kb + g * 8;
            bf16x8 vf0 = *(const bf16x8*)vb;
            bf16x8 vf1 = *(const bf16x8*)(vb + 32);
            oacc[dc] = __builtin_amdgcn_mfma_f32_16x16x32_bf16(pa0, vf0, oacc[dc], 0, 0, 0);
            oacc[dc] = __builtin_amdgcn_mfma_f32_16x16x32_bf16(pa1, vf1, oacc[dc], 0, 0, 0);
        }
    }
    #pragma unroll
    for (int dc = 0; dc < 8; ++dc)
        #pragma unroll
        for (int r = 0; r < 4; ++r) {
            int qrow = q0 + g * 4 + r;
            float o = oacc[dc][r] / lrun[r];
            ctx[(size_t)qrow * 4096 + h * 128 + dc * 16 + l15] = f2b(o);
        }
}

extern "C" void kernel_launch(void* const* d_in, const int* in_sizes, int n_in,
                              void* d_out, int out_size, void* d_ws, size_t ws_size,
                              hipStream_t stream) {
    const float* hs  = (const float*)d_in[0];
    const int* tt    = (const int*)d_in[1];
    const int* pos   = (const int*)d_in[2];
    const float* wqv = (const float*)d_in[3];
    const float* wql = (const float*)d_in[4];
    const float* wov = (const float*)d_in[5];
    const float* wol = (const float*)d_in[6];
    const float* invf= (const float*)d_in[7];
    float* out = (float*)d_out;

    const int S = 2048, D = 4096, K = 4096, N3 = 12288;

    char* ws = (char*)d_ws;
    size_t off = 0;
    auto alloc = [&](size_t bytes) {
        void* p = ws + off;
        off += (bytes + 255) & ~(size_t)255;
        return p;
    };
    unsigned char* mask = (unsigned char*)alloc(S);
    float* ct = (float*)alloc((size_t)S * 64 * 4);
    float* st = (float*)alloc((size_t)S * 64 * 4);
    unsigned short* hbf  = (unsigned short*)alloc((size_t)S * D * 2);
    unsigned short* qkv  = (unsigned short*)alloc((size_t)S * N3 * 2);
    unsigned short* vt   = (unsigned short*)alloc((size_t)S * D * 2);
    unsigned short* ctx  = (unsigned short*)alloc((size_t)S * D * 2);
    unsigned short* wbuf = (unsigned short*)alloc((size_t)N3 * K * 2);
    (void)ws_size; (void)n_in; (void)in_sizes; (void)out_size;

    prep_kernel<<<(S * 64 + 255) / 256, 256, 0, stream>>>(tt, pos, invf, mask, ct, st, S);
    cvt_f32_bf16<<<8192, 256, 0, stream>>>(hs, hbf, (long)S * D);

    cvt_f32_bf16<<<16384, 256, 0, stream>>>(wqv, wbuf, (long)N3 * K);
    gemm_bt_masked<1><<<dim3(96, 16), 256, 0, stream>>>(hbf, wbuf, qkv, S, N3, K, mask, 1);
    cvt_f32_bf16<<<16384, 256, 0, stream>>>(wql, wbuf, (long)N3 * K);
    gemm_bt_masked<1><<<dim3(96, 16), 256, 0, stream>>>(hbf, wbuf, qkv, S, N3, K, mask, 0);

    rope_kernel<<<(S * 32 * 16 + 255) / 256, 256, 0, stream>>>(qkv, ct, st, S);
    transpose_v<<<dim3(S / 64, D / 64), 256, 0, stream>>>(qkv, vt, S);
    attn_kernel<<<dim3(32, S / 64), 256, 0, stream>>>(qkv, vt, ctx, S);

    cvt_f32_bf16<<<16384, 256, 0, stream>>>(wov, wbuf, (long)D * K);
    gemm_bt_masked<0><<<dim3(32, 16), 256, 0, stream>>>(ctx, wbuf, out, S, D, K, mask, 1);
    cvt_f32_bf16<<<16384, 256, 0, stream>>>(wol, wbuf, (long)D * K);
    gemm_bt_masked<0><<<dim3(32, 16), 256, 0, stream>>>(ctx, wbuf, out, S, D, K, mask, 0);
}